// Round 5
// baseline (304.446 us; speedup 1.0000x reference)
//
#include <hip/hip_runtime.h>

#define BATCH 8192
#define MDIM 128
#define NL 10
#define LSTEPS 97
#define RSTEPS 96
#define NSTEPS 193   // LSTEPS + RSTEPS
#define DIM 196
#define POSL 98

typedef _Float16 half8 __attribute__((ext_vector_type(8)));
typedef float float16v __attribute__((ext_vector_type(16)));

// The one barrier used inside the chain K-loop. vmcnt(6) = the 6 newest vm-ops
// (next A-half 4 + x 2) may stay in flight; everything older (the half-buffer
// we are about to read, issued 2 halves ago) must have landed. lgkmcnt(0)
// orders carry LDS writes/reads. NEVER vmcnt(0) -> global pipe stays fed.
#define WAITBAR() asm volatile("s_waitcnt vmcnt(6) lgkmcnt(0)\ns_barrier" ::: "memory")

__device__ __forceinline__ void dma16(const void* g, void* l) {
    __builtin_amdgcn_global_load_lds(
        (const __attribute__((address_space(1))) void*)g,
        (__attribute__((address_space(3))) void*)l, 16, 0, 0);
}
__device__ __forceinline__ void dma4(const void* g, void* l) {
    __builtin_amdgcn_global_load_lds(
        (const __attribute__((address_space(1))) void*)g,
        (__attribute__((address_space(3))) void*)l, 4, 0, 0);
}

// ---------------------------------------------------------------------------
// Pack chain weights into f16 A-fragment order, K-half-major so each 32 KB
// half-K block is contiguous: pw[((g*2+s)*32 + nt*8 + kt7)*512 + l*8 + j]
// holds W_g[k = (s*8+kt7)*16 + (l>>5)*8 + j][n = nt*32 + (l&31)].
// ---------------------------------------------------------------------------
__global__ __launch_bounds__(256) void pack_w(const float* __restrict__ w_left,
                                              const float* __restrict__ w_right,
                                              _Float16* __restrict__ pw) {
    int g = blockIdx.x >> 2;
    int nt = blockIdx.x & 3;
    int tid = threadIdx.x;
    int l = tid & 63;
    int kq = tid >> 6;
    int hi = l >> 5;
    int n = nt * 32 + (l & 31);
#pragma unroll
    for (int p = 0; p < 4; ++p) {
        int kt = p * 4 + kq;               // global kt 0..15
        int s = kt >> 3, kt7 = kt & 7;
        int k0 = kt * 16 + hi * 8;
        half8 hv;
        if (g < LSTEPS) {
            const float* base = w_left + (size_t)g * 2 * MDIM * MDIM;
#pragma unroll
            for (int j = 0; j < 8; ++j)
                hv[j] = (_Float16)base[(size_t)(k0 + j) * MDIM + n];
        } else {
            int t = g - LSTEPS;
            int a0 = k0 & 127;
            const float* row = w_right + (size_t)(RSTEPS - 1 - t) * 2 * MDIM * MDIM
                             + (size_t)s * MDIM * MDIM + (size_t)n * MDIM + a0;
#pragma unroll
            for (int j = 0; j < 8; ++j) hv[j] = (_Float16)row[j];
        }
        *(half8*)(pw + (size_t)((g * 2 + s) * 32 + nt * 8 + kt7) * 512 + l * 8) = hv;
    }
}

// ---------------------------------------------------------------------------
// Pack w_label into f16 A-frag order with l-major columns (unchanged).
// ---------------------------------------------------------------------------
__global__ __launch_bounds__(256) void pack_label(const float* __restrict__ w_label,
                                                  _Float16* __restrict__ gp) {
    int ct = blockIdx.x;               // 0..39
    int tid = threadIdx.x;
    int l = tid & 63;
    int kq = tid >> 6;
    int hi = l >> 5;
    int outcol = ct * 32 + (l & 31);
    int n = outcol & 127;
    int lab = outcol >> 7;
#pragma unroll
    for (int p2 = 0; p2 < 4; ++p2) {
        int kt = p2 * 4 + kq;
        int k0 = kt * 16 + hi * 8;
        int p = k0 >> 7;
        int m0 = k0 & 127;
        half8 hv;
#pragma unroll
        for (int j = 0; j < 8; ++j)
            hv[j] = (_Float16)w_label[(((size_t)p * MDIM + m0 + j) * MDIM + n) * NL + lab];
        *(half8*)(gp + (size_t)(ct * 16 + kt) * 512 + l * 8) = hv;
    }
}

// ---------------------------------------------------------------------------
// Chain kernel v5: 256 blocks x 512 threads, 1 block/CU, 8 waves (4 nt x 2 bh).
// Half-K (32 KB) DMA blocks in a 4-slot LDS ring, one WAITBAR per half-step
// with constant vmcnt(6): the ring always has ~1.5 half-blocks in flight, the
// pipe never drains. x values ride the same DMA path into a 4-slot LDS ring
// (no compiler-tracked global loads inside the loop).
// ---------------------------------------------------------------------------
__global__ __launch_bounds__(512, 2) void chain_mfma(
        const float* __restrict__ x, const float* __restrict__ w0,
        const float* __restrict__ w_end, const _Float16* __restrict__ pw,
        float* __restrict__ leftT, float* __restrict__ rightT) {
    __shared__ _Float16 Aring[4][16384];     // 4 x 32 KB
    __shared__ _Float16 cbuf[64 * 128];      // 16 KB carry (in-place)
    __shared__ float xring[4][64][2];        // 2 KB x staging

    int bid = blockIdx.x;
    bool is_left = bid < 128;
    int bbase = (is_left ? bid : bid - 128) * 64;
    int tid = threadIdx.x;
    int l = tid & 63;
    int wv = tid >> 6;        // 0..7
    int nt = wv & 3;          // n-tile
    int bh = wv >> 2;         // b-half
    int bl = l & 31;
    int hi = l >> 5;
    int brow = bh * 32 + bl;  // block-local batch row

    int nsteps = is_left ? LSTEPS : RSTEPS;
    int gbase = is_left ? 0 : LSTEPS;
    float* outT = is_left ? leftT : rightT;

    // --- initial carry: c0[b][n] = x0*wstart[0][n] + x1*wstart[1][n]
    {
        const float* wst = is_left ? w0 : w_end;
        int pos0 = is_left ? 0 : (DIM - 1);
        int b = tid >> 3;
        const float2 xv0 = *(const float2*)(x + ((size_t)(bbase + b) * DIM + pos0) * 2);
#pragma unroll
        for (int h = 0; h < 2; ++h) {
            int nb = (tid & 7) * 2 + h;
            half8 hv;
#pragma unroll
            for (int j = 0; j < 8; ++j) {
                int n = nb * 8 + j;
                hv[j] = (_Float16)(xv0.x * wst[n] + xv0.y * wst[MDIM + n]);
            }
            int phys = nb ^ (b & 15);
            *(half8*)&cbuf[b * 128 + phys * 8] = hv;
        }
    }

    // per-lane x gather bases (row = l>>1, elem = l&1; second instr rows +32)
    const float* xb0 = x + (size_t)(bbase + (l >> 1)) * DIM * 2 + (l & 1);
    const float* xb1 = xb0 + (size_t)32 * DIM * 2;

    // A-half DMA: half h -> slot h&3 (4 instrs/wave, wave covers 4 KB)
    auto issueA = [&](int h) {
        int sg = h >> 1; if (sg > nsteps - 1) sg = nsteps - 1;
        const char* src = (const char*)pw
            + (size_t)((gbase + sg) * 2 + (h & 1)) * 32768 + wv * 4096 + (size_t)l * 16;
        char* dst = (char*)&Aring[h & 3][0] + wv * 4096;
#pragma unroll
        for (int r = 0; r < 4; ++r) dma16(src + r * 1024, dst + r * 1024);
    };
    // x DMA for step s -> slot s&3 (2 instrs, all waves duplicate: uniform vmcnt)
    auto issueX = [&](int s) {
        int sc = s > nsteps - 1 ? nsteps - 1 : s;
        int pos = is_left ? (1 + sc) : (DIM - 2 - sc);
        dma4(xb0 + (size_t)pos * 2, &xring[s & 3][0][0]);
        dma4(xb1 + (size_t)pos * 2, &xring[s & 3][32][0]);
    };

    // prologue priming — order fixes ages so vmcnt(6) is exact at h=0:
    // [x(0)(2), A(0)(4), x(1)(2), A(1)(4)] -> newest 6 = x(1)+A(1)
    issueX(0); issueA(0); issueX(1); issueA(1);

#pragma unroll 1
    for (int step = 0; step < nsteps; ++step) {
        // ---- even half: slot (2s)&3 valid after this barrier ----
        WAITBAR();
        issueA(2 * step + 2);
        issueX(step + 2);

        half8 bf[8];
#pragma unroll
        for (int q = 0; q < 8; ++q) {
            int nb = q * 2 + hi;
            int phys = nb ^ (brow & 15);
            bf[q] = *(const half8*)&cbuf[brow * 128 + phys * 8];
        }

        const _Float16* Ae = &Aring[(step & 1) << 1][0];
        float16v acc0 = {};
#pragma unroll
        for (int kt = 0; kt < 8; ++kt) {
            half8 a = *(const half8*)&Ae[(size_t)(nt * 8 + kt) * 512 + l * 8];
            acc0 = __builtin_amdgcn_mfma_f32_32x32x16_f16(a, bf[kt], acc0, 0, 0, 0);
        }

        // ---- odd half: slot (2s+1)&3 valid after this barrier ----
        WAITBAR();
        issueA(2 * step + 3);

        const _Float16* Ao = &Aring[((step & 1) << 1) + 1][0];
        float16v acc1 = {};
#pragma unroll
        for (int kt = 0; kt < 8; ++kt) {
            half8 a = *(const half8*)&Ao[(size_t)(nt * 8 + kt) * 512 + l * 8];
            acc1 = __builtin_amdgcn_mfma_f32_32x32x16_f16(a, bf[kt], acc1, 0, 0, 0);
        }

        const float2 xc = *(const float2*)&xring[step & 3][brow][0];

        if (step + 1 < nsteps) {
            // epilogue: c_new = x0*acc0 + x1*acc1 (fp32), cvt f16, swizzled 8B writes
#pragma unroll
            for (int rq = 0; rq < 4; ++rq) {
                int nb = nt * 4 + rq;
                int phys = nb ^ (brow & 15);
                union { _Float16 h[4]; uint2 u; } t;
#pragma unroll
                for (int r = 0; r < 4; ++r)
                    t.h[r] = (_Float16)(xc.x * acc0[rq * 4 + r] + xc.y * acc1[rq * 4 + r]);
                *(uint2*)&cbuf[brow * 128 + phys * 8 + hi * 4] = t.u;
            }
        } else {
            // final step: store fp32 transposed [n][BATCH] (coalesced)
#pragma unroll
            for (int r = 0; r < 16; ++r) {
                int n = nt * 32 + (r & 3) + 8 * (r >> 2) + 4 * hi;
                outT[(size_t)n * BATCH + bbase + brow] = xc.x * acc0[r] + xc.y * acc1[r];
            }
        }
    }
}

// ---------------------------------------------------------------------------
// Label contraction via MFMA (unchanged from round 3/4).
// ---------------------------------------------------------------------------
__global__ __launch_bounds__(256, 2) void label_mfma(
        const float* __restrict__ x, const _Float16* __restrict__ gp,
        const float* __restrict__ leftT, const float* __restrict__ rightT,
        float* __restrict__ out) {
    __shared__ _Float16 R[32 * 256];     // 16 KB
    __shared__ float pl[4][32][5];
    __shared__ float xl_s[32][2];

    int bx = blockIdx.x;                 // 0/1 -> labels [bx*5, +5)
    int bbase = blockIdx.y * 32;
    int tid = threadIdx.x;
    int l = tid & 63, nt = tid >> 6, bl = l & 31, hi = l >> 5;

    if (tid < 32) {
        const float2 v = *(const float2*)(x + ((size_t)(bbase + tid) * DIM + POSL) * 2);
        xl_s[tid][0] = v.x; xl_s[tid][1] = v.y;
    }
    __syncthreads();

#pragma unroll
    for (int q = 0; q < 4; ++q) {
        int id = tid + q * 256;          // 0..1023
        int m = id >> 3;
        int b4 = (id & 7) * 4;
        float4 v = *(const float4*)&leftT[(size_t)m * BATCH + bbase + b4];
        float vv[4] = {v.x, v.y, v.z, v.w};
#pragma unroll
        for (int bi = 0; bi < 4; ++bi) {
            int b = b4 + bi;
            int kb0 = m >> 3;
            int ph0 = (kb0 & 16) | ((kb0 ^ b) & 15);
            R[b * 256 + ph0 * 8 + (m & 7)] = (_Float16)(xl_s[b][0] * vv[bi]);
            int kb1 = kb0 + 16;
            int ph1 = (kb1 & 16) | ((kb1 ^ b) & 15);
            R[b * 256 + ph1 * 8 + (m & 7)] = (_Float16)(xl_s[b][1] * vv[bi]);
        }
    }

    float rv[16];
#pragma unroll
    for (int r = 0; r < 16; ++r) {
        int n = nt * 32 + (r & 3) + 8 * (r >> 2) + 4 * hi;
        rv[r] = rightT[(size_t)n * BATCH + bbase + bl];
    }
    __syncthreads();

    half8 rf[16];
#pragma unroll
    for (int kt = 0; kt < 16; ++kt) {
        int kb = kt * 2 + hi;
        int ph = (kb & 16) | ((kb ^ bl) & 15);
        rf[kt] = *(const half8*)&R[bl * 256 + ph * 8];
    }

    int l0 = bx * 5;
    float outv[5];
#pragma unroll
    for (int li = 0; li < 5; ++li) {
        int ct = (l0 + li) * 4 + nt;
        float16v acc = {};
#pragma unroll
        for (int kt = 0; kt < 16; ++kt) {
            half8 a = *(const half8*)(gp + (size_t)(ct * 16 + kt) * 512 + l * 8);
            acc = __builtin_amdgcn_mfma_f32_32x32x16_f16(a, rf[kt], acc, 0, 0, 0);
        }
        float p = 0.f;
#pragma unroll
        for (int r = 0; r < 16; ++r) p += acc[r] * rv[r];
        p += __shfl_xor(p, 32, 64);
        outv[li] = p;
    }
    if (hi == 0) {
#pragma unroll
        for (int li = 0; li < 5; ++li) pl[nt][bl][li] = outv[li];
    }
    __syncthreads();
    if (tid < 160) {
        int b = tid / 5, li = tid % 5;
        out[(size_t)(bbase + b) * NL + l0 + li] =
            pl[0][b][li] + pl[1][b][li] + pl[2][b][li] + pl[3][b][li];
    }
}

// ---------------------------------------------------------------------------
extern "C" void kernel_launch(void* const* d_in, const int* in_sizes, int n_in,
                              void* d_out, int out_size, void* d_ws, size_t ws_size,
                              hipStream_t stream) {
    const float* x       = (const float*)d_in[0];
    const float* w0      = (const float*)d_in[1];
    const float* w_left  = (const float*)d_in[2];
    const float* w_label = (const float*)d_in[3];
    const float* w_right = (const float*)d_in[4];
    const float* w_end   = (const float*)d_in[5];

    _Float16* pw = (_Float16*)d_ws;                               // 12.64 MB
    _Float16* gp = pw + (size_t)NSTEPS * 64 * 512;                // 0.66 MB
    float* leftT  = (float*)(gp + (size_t)40 * 16 * 512);         // 4 MB
    float* rightT = leftT + (size_t)MDIM * BATCH;                 // 4 MB

    pack_w<<<dim3(NSTEPS * 4), 256, 0, stream>>>(w_left, w_right, pw);
    pack_label<<<dim3(40), 256, 0, stream>>>(w_label, gp);
    chain_mfma<<<dim3(256), 512, 0, stream>>>(x, w0, w_end, pw, leftT, rightT);
    label_mfma<<<dim3(2, BATCH / 32), 256, 0, stream>>>(x, gp, leftT, rightT,
                                                        (float*)d_out);
}

// Round 6
// 244.423 us; speedup vs baseline: 1.2456x; 1.2456x over previous
//
#include <hip/hip_runtime.h>

#define BATCH 8192
#define MDIM 128
#define NL 10
#define LSTEPS 97
#define RSTEPS 96
#define NSTEPS 193   // LSTEPS + RSTEPS
#define DIM 196
#define POSL 98

typedef _Float16 half8 __attribute__((ext_vector_type(8)));
typedef float float16v __attribute__((ext_vector_type(16)));

// lgkm-only barrier: orders LDS ops; never drains vmcnt (register prefetches fly).
#define BARRIER_LGKM() asm volatile("s_waitcnt lgkmcnt(0)\ns_barrier" ::: "memory")

// ---------------------------------------------------------------------------
// Pack chain weights into f16 A-fragment order for v_mfma_f32_32x32x16_f16
// (round-3/4 full-K layout): pw[(g*64 + nt*16 + kt)*512 + l*8 + j]
//  = W_g[k = kt*16 + (l>>5)*8 + j][n = nt*32 + (l&31)]
// left (g<97): W_g[k=s*128+m][n] = w_left[g][s][m][n]
// right(g>=97): t=g-97, W_g[k=s*128+a][n] = w_right[95-t][s][n][a]
// ---------------------------------------------------------------------------
__global__ __launch_bounds__(256) void pack_w(const float* __restrict__ w_left,
                                              const float* __restrict__ w_right,
                                              _Float16* __restrict__ pw) {
    int g = blockIdx.x >> 2;
    int nt = blockIdx.x & 3;
    int tid = threadIdx.x;
    int l = tid & 63;
    int kq = tid >> 6;
    int hi = l >> 5;
    int n = nt * 32 + (l & 31);
#pragma unroll
    for (int p = 0; p < 4; ++p) {
        int kt = p * 4 + kq;
        int k0 = kt * 16 + hi * 8;
        half8 hv;
        if (g < LSTEPS) {
            const float* base = w_left + (size_t)g * 2 * MDIM * MDIM;
#pragma unroll
            for (int j = 0; j < 8; ++j)
                hv[j] = (_Float16)base[(size_t)(k0 + j) * MDIM + n];
        } else {
            int t = g - LSTEPS;
            int s = k0 >> 7;
            int a0 = k0 & 127;
            const float* row = w_right + (size_t)(RSTEPS - 1 - t) * 2 * MDIM * MDIM
                             + (size_t)s * MDIM * MDIM + (size_t)n * MDIM + a0;
#pragma unroll
            for (int j = 0; j < 8; ++j) hv[j] = (_Float16)row[j];
        }
        *(half8*)(pw + (size_t)(g * 64 + nt * 16 + kt) * 512 + l * 8) = hv;
    }
}

// ---------------------------------------------------------------------------
// Pack w_label into f16 A-frag order with l-major columns (unchanged).
// ---------------------------------------------------------------------------
__global__ __launch_bounds__(256) void pack_label(const float* __restrict__ w_label,
                                                  _Float16* __restrict__ gp) {
    int ct = blockIdx.x;               // 0..39
    int tid = threadIdx.x;
    int l = tid & 63;
    int kq = tid >> 6;
    int hi = l >> 5;
    int outcol = ct * 32 + (l & 31);
    int n = outcol & 127;
    int lab = outcol >> 7;
#pragma unroll
    for (int p2 = 0; p2 < 4; ++p2) {
        int kt = p2 * 4 + kq;
        int k0 = kt * 16 + hi * 8;
        int p = k0 >> 7;
        int m0 = k0 & 127;
        half8 hv;
#pragma unroll
        for (int j = 0; j < 8; ++j)
            hv[j] = (_Float16)w_label[(((size_t)p * MDIM + m0 + j) * MDIM + n) * NL + lab];
        *(half8*)(gp + (size_t)(ct * 16 + kt) * 512 + l * 8) = hv;
    }
}

// ---------------------------------------------------------------------------
// Chain kernel v6: 256 blocks x 512 threads, 8 waves (4 nt x 2 bh).
// A operand lives in REGISTERS (A0/A1 double buffer, pair-unrolled loop),
// prefetched one full step ahead via plain global loads — no LDS round-trip
// for A, no vm drains. Carry double-buffered in LDS (2 x 16 KB), ONE
// lgkm-only barrier per step. launch_bounds(512,2) -> 256-VGPR budget.
// ---------------------------------------------------------------------------
__global__ __launch_bounds__(512, 2) void chain_mfma(
        const float* __restrict__ x, const float* __restrict__ w0,
        const float* __restrict__ w_end, const _Float16* __restrict__ pw,
        float* __restrict__ leftT, float* __restrict__ rightT) {
    __shared__ _Float16 cbuf[2][64 * 128];   // 2 x 16 KB carry

    int bid = blockIdx.x;
    bool is_left = bid < 128;
    int bbase = (is_left ? bid : bid - 128) * 64;
    int tid = threadIdx.x;
    int l = tid & 63;
    int wv = tid >> 6;        // 0..7
    int nt = wv & 3;          // n-tile (twins share nt -> same A addresses, L1 hits)
    int bh = wv >> 2;         // b-half
    int bl = l & 31;
    int hi = l >> 5;
    int brow = bh * 32 + bl;  // block-local batch row

    int nsteps = is_left ? LSTEPS : RSTEPS;
    int gbase = is_left ? 0 : LSTEPS;
    float* outT = is_left ? leftT : rightT;

    // --- initial carry into cbuf[0]
    {
        const float* wst = is_left ? w0 : w_end;
        int pos0 = is_left ? 0 : (DIM - 1);
        int b = tid >> 3;
        const float2 xv0 = *(const float2*)(x + ((size_t)(bbase + b) * DIM + pos0) * 2);
#pragma unroll
        for (int h = 0; h < 2; ++h) {
            int nb = (tid & 7) * 2 + h;
            half8 hv;
#pragma unroll
            for (int j = 0; j < 8; ++j) {
                int n = nb * 8 + j;
                hv[j] = (_Float16)(xv0.x * wst[n] + xv0.y * wst[MDIM + n]);
            }
            int phys = nb ^ (b & 15);
            *(half8*)&cbuf[0][b * 128 + phys * 8] = hv;
        }
    }

    // per-wave A base: frag kt at pwb + step*65536 + kt*1024
    const char* pwb = (const char*)pw + (size_t)(gbase * 64 + nt * 16) * 1024
                    + (size_t)l * 16;
    const float* xrow = x + (size_t)(bbase + brow) * DIM * 2;

    half8 A0[16], A1[16];
#pragma unroll
    for (int kt = 0; kt < 16; ++kt)
        A0[kt] = *(const half8*)(pwb + kt * 1024);
    float2 xcur = *(const float2*)(xrow + (is_left ? 1 : DIM - 2) * 2);

    __syncthreads();   // carry init visible

    int npairs = nsteps >> 1;          // 48 for both chains
    bool odd = nsteps & 1;             // left: 1, right: 0
    int last = nsteps - 1;

#pragma unroll 1
    for (int sp = 0; sp < npairs; ++sp) {
        int s0 = 2 * sp;
        // ---------- even step s0: consume A0, prefetch A1 <- step s0+1 ----------
        {
            const char* pn = pwb + (size_t)(s0 + 1) * 65536;
#pragma unroll
            for (int kt = 0; kt < 16; ++kt)
                A1[kt] = *(const half8*)(pn + kt * 1024);
            int npos = is_left ? (2 + s0) : (DIM - 3 - s0);
            float2 xnext = *(const float2*)(xrow + (size_t)npos * 2);

            half8 bf[8];
#pragma unroll
            for (int q = 0; q < 8; ++q) {
                int nb = q * 2 + hi;
                int phys = nb ^ (brow & 15);
                bf[q] = *(const half8*)&cbuf[0][brow * 128 + phys * 8];
            }
            float16v acc0 = {}, acc1 = {};
#pragma unroll
            for (int kt = 0; kt < 8; ++kt) {
                acc0 = __builtin_amdgcn_mfma_f32_32x32x16_f16(A0[kt], bf[kt], acc0, 0, 0, 0);
                acc1 = __builtin_amdgcn_mfma_f32_32x32x16_f16(A0[kt + 8], bf[kt], acc1, 0, 0, 0);
            }
            // even step is never the final step (final is odd idx when nsteps even,
            // and handled in tail when nsteps odd)
#pragma unroll
            for (int rq = 0; rq < 4; ++rq) {
                int nb = nt * 4 + rq;
                int phys = nb ^ (brow & 15);
                union { _Float16 h[4]; uint2 u; } t;
#pragma unroll
                for (int r = 0; r < 4; ++r)
                    t.h[r] = (_Float16)(xcur.x * acc0[rq * 4 + r] + xcur.y * acc1[rq * 4 + r]);
                *(uint2*)&cbuf[1][brow * 128 + phys * 8 + hi * 4] = t.u;
            }
            BARRIER_LGKM();
            xcur = xnext;
        }
        // ---------- odd step s1 = s0+1: consume A1, prefetch A0 <- s0+2 ----------
        {
            int s1 = s0 + 1;
            int pf = (s0 + 2 <= last) ? (s0 + 2) : last;   // clamp (harmless reload)
            const char* pn = pwb + (size_t)pf * 65536;
#pragma unroll
            for (int kt = 0; kt < 16; ++kt)
                A0[kt] = *(const half8*)(pn + kt * 1024);
            int nposc = is_left ? (1 + pf) : (DIM - 2 - pf);
            float2 xnext = *(const float2*)(xrow + (size_t)nposc * 2);

            half8 bf[8];
#pragma unroll
            for (int q = 0; q < 8; ++q) {
                int nb = q * 2 + hi;
                int phys = nb ^ (brow & 15);
                bf[q] = *(const half8*)&cbuf[1][brow * 128 + phys * 8];
            }
            float16v acc0 = {}, acc1 = {};
#pragma unroll
            for (int kt = 0; kt < 8; ++kt) {
                acc0 = __builtin_amdgcn_mfma_f32_32x32x16_f16(A1[kt], bf[kt], acc0, 0, 0, 0);
                acc1 = __builtin_amdgcn_mfma_f32_32x32x16_f16(A1[kt + 8], bf[kt], acc1, 0, 0, 0);
            }
            if (s1 == last) {
                // final step (right chain): store fp32 transposed [n][BATCH]
#pragma unroll
                for (int r = 0; r < 16; ++r) {
                    int n = nt * 32 + (r & 3) + 8 * (r >> 2) + 4 * hi;
                    outT[(size_t)n * BATCH + bbase + brow] = xcur.x * acc0[r] + xcur.y * acc1[r];
                }
            } else {
#pragma unroll
                for (int rq = 0; rq < 4; ++rq) {
                    int nb = nt * 4 + rq;
                    int phys = nb ^ (brow & 15);
                    union { _Float16 h[4]; uint2 u; } t;
#pragma unroll
                    for (int r = 0; r < 4; ++r)
                        t.h[r] = (_Float16)(xcur.x * acc0[rq * 4 + r] + xcur.y * acc1[rq * 4 + r]);
                    *(uint2*)&cbuf[0][brow * 128 + phys * 8 + hi * 4] = t.u;
                }
                BARRIER_LGKM();
            }
            xcur = xnext;
        }
    }

    if (odd) {   // tail step = nsteps-1 (even index; left chain), consume A0
        half8 bf[8];
#pragma unroll
        for (int q = 0; q < 8; ++q) {
            int nb = q * 2 + hi;
            int phys = nb ^ (brow & 15);
            bf[q] = *(const half8*)&cbuf[0][brow * 128 + phys * 8];
        }
        float16v acc0 = {}, acc1 = {};
#pragma unroll
        for (int kt = 0; kt < 8; ++kt) {
            acc0 = __builtin_amdgcn_mfma_f32_32x32x16_f16(A0[kt], bf[kt], acc0, 0, 0, 0);
            acc1 = __builtin_amdgcn_mfma_f32_32x32x16_f16(A0[kt + 8], bf[kt], acc1, 0, 0, 0);
        }
#pragma unroll
        for (int r = 0; r < 16; ++r) {
            int n = nt * 32 + (r & 3) + 8 * (r >> 2) + 4 * hi;
            outT[(size_t)n * BATCH + bbase + brow] = xcur.x * acc0[r] + xcur.y * acc1[r];
        }
    }
}

// ---------------------------------------------------------------------------
// Label contraction via MFMA (unchanged from rounds 3-5).
// ---------------------------------------------------------------------------
__global__ __launch_bounds__(256, 2) void label_mfma(
        const float* __restrict__ x, const _Float16* __restrict__ gp,
        const float* __restrict__ leftT, const float* __restrict__ rightT,
        float* __restrict__ out) {
    __shared__ _Float16 R[32 * 256];     // 16 KB
    __shared__ float pl[4][32][5];
    __shared__ float xl_s[32][2];

    int bx = blockIdx.x;                 // 0/1 -> labels [bx*5, +5)
    int bbase = blockIdx.y * 32;
    int tid = threadIdx.x;
    int l = tid & 63, nt = tid >> 6, bl = l & 31, hi = l >> 5;

    if (tid < 32) {
        const float2 v = *(const float2*)(x + ((size_t)(bbase + tid) * DIM + POSL) * 2);
        xl_s[tid][0] = v.x; xl_s[tid][1] = v.y;
    }
    __syncthreads();

#pragma unroll
    for (int q = 0; q < 4; ++q) {
        int id = tid + q * 256;          // 0..1023
        int m = id >> 3;
        int b4 = (id & 7) * 4;
        float4 v = *(const float4*)&leftT[(size_t)m * BATCH + bbase + b4];
        float vv[4] = {v.x, v.y, v.z, v.w};
#pragma unroll
        for (int bi = 0; bi < 4; ++bi) {
            int b = b4 + bi;
            int kb0 = m >> 3;
            int ph0 = (kb0 & 16) | ((kb0 ^ b) & 15);
            R[b * 256 + ph0 * 8 + (m & 7)] = (_Float16)(xl_s[b][0] * vv[bi]);
            int kb1 = kb0 + 16;
            int ph1 = (kb1 & 16) | ((kb1 ^ b) & 15);
            R[b * 256 + ph1 * 8 + (m & 7)] = (_Float16)(xl_s[b][1] * vv[bi]);
        }
    }

    float rv[16];
#pragma unroll
    for (int r = 0; r < 16; ++r) {
        int n = nt * 32 + (r & 3) + 8 * (r >> 2) + 4 * hi;
        rv[r] = rightT[(size_t)n * BATCH + bbase + bl];
    }
    __syncthreads();

    half8 rf[16];
#pragma unroll
    for (int kt = 0; kt < 16; ++kt) {
        int kb = kt * 2 + hi;
        int ph = (kb & 16) | ((kb ^ bl) & 15);
        rf[kt] = *(const half8*)&R[bl * 256 + ph * 8];
    }

    int l0 = bx * 5;
    float outv[5];
#pragma unroll
    for (int li = 0; li < 5; ++li) {
        int ct = (l0 + li) * 4 + nt;
        float16v acc = {};
#pragma unroll
        for (int kt = 0; kt < 16; ++kt) {
            half8 a = *(const half8*)(gp + (size_t)(ct * 16 + kt) * 512 + l * 8);
            acc = __builtin_amdgcn_mfma_f32_32x32x16_f16(a, rf[kt], acc, 0, 0, 0);
        }
        float p = 0.f;
#pragma unroll
        for (int r = 0; r < 16; ++r) p += acc[r] * rv[r];
        p += __shfl_xor(p, 32, 64);
        outv[li] = p;
    }
    if (hi == 0) {
#pragma unroll
        for (int li = 0; li < 5; ++li) pl[nt][bl][li] = outv[li];
    }
    __syncthreads();
    if (tid < 160) {
        int b = tid / 5, li = tid % 5;
        out[(size_t)(bbase + b) * NL + l0 + li] =
            pl[0][b][li] + pl[1][b][li] + pl[2][b][li] + pl[3][b][li];
    }
}

// ---------------------------------------------------------------------------
extern "C" void kernel_launch(void* const* d_in, const int* in_sizes, int n_in,
                              void* d_out, int out_size, void* d_ws, size_t ws_size,
                              hipStream_t stream) {
    const float* x       = (const float*)d_in[0];
    const float* w0      = (const float*)d_in[1];
    const float* w_left  = (const float*)d_in[2];
    const float* w_label = (const float*)d_in[3];
    const float* w_right = (const float*)d_in[4];
    const float* w_end   = (const float*)d_in[5];

    _Float16* pw = (_Float16*)d_ws;                               // 12.64 MB
    _Float16* gp = pw + (size_t)NSTEPS * 64 * 512;                // 0.66 MB
    float* leftT  = (float*)(gp + (size_t)40 * 16 * 512);         // 4 MB
    float* rightT = leftT + (size_t)MDIM * BATCH;                 // 4 MB

    pack_w<<<dim3(NSTEPS * 4), 256, 0, stream>>>(w_left, w_right, pw);
    pack_label<<<dim3(40), 256, 0, stream>>>(w_label, gp);
    chain_mfma<<<dim3(256), 512, 0, stream>>>(x, w0, w_end, pw, leftT, rightT);
    label_mfma<<<dim3(2, BATCH / 32), 256, 0, stream>>>(x, gp, leftT, rightT,
                                                        (float*)d_out);
}

// Round 7
// 237.424 us; speedup vs baseline: 1.2823x; 1.0295x over previous
//
#include <hip/hip_runtime.h>

#define BATCH 8192
#define MDIM 128
#define NL 10
#define LSTEPS 97
#define RSTEPS 96
#define NSTEPS 193   // LSTEPS + RSTEPS
#define DIM 196
#define POSL 98

typedef _Float16 half8 __attribute__((ext_vector_type(8)));
typedef float float16v __attribute__((ext_vector_type(16)));

// lgkm-only barrier: orders LDS ops; never drains vmcnt (register prefetches fly).
#define BARRIER_LGKM() asm volatile("s_waitcnt lgkmcnt(0)\ns_barrier" ::: "memory")

// ---------------------------------------------------------------------------
// Pack chain weights into f16 A-fragment order for v_mfma_f32_32x32x16_f16:
// pw[(g*64 + nt*16 + kt)*512 + l*8 + j] = W_g[k=kt*16+(l>>5)*8+j][n=nt*32+(l&31)]
// left (g<97): W_g[k=s*128+m][n] = w_left[g][s][m][n]
// right(g>=97): t=g-97, W_g[k=s*128+a][n] = w_right[95-t][s][n][a]
// ---------------------------------------------------------------------------
__global__ __launch_bounds__(256) void pack_w(const float* __restrict__ w_left,
                                              const float* __restrict__ w_right,
                                              _Float16* __restrict__ pw) {
    int g = blockIdx.x >> 2;
    int nt = blockIdx.x & 3;
    int tid = threadIdx.x;
    int l = tid & 63;
    int kq = tid >> 6;
    int hi = l >> 5;
    int n = nt * 32 + (l & 31);
#pragma unroll
    for (int p = 0; p < 4; ++p) {
        int kt = p * 4 + kq;
        int k0 = kt * 16 + hi * 8;
        half8 hv;
        if (g < LSTEPS) {
            const float* base = w_left + (size_t)g * 2 * MDIM * MDIM;
#pragma unroll
            for (int j = 0; j < 8; ++j)
                hv[j] = (_Float16)base[(size_t)(k0 + j) * MDIM + n];
        } else {
            int t = g - LSTEPS;
            int s = k0 >> 7;
            int a0 = k0 & 127;
            const float* row = w_right + (size_t)(RSTEPS - 1 - t) * 2 * MDIM * MDIM
                             + (size_t)s * MDIM * MDIM + (size_t)n * MDIM + a0;
#pragma unroll
            for (int j = 0; j < 8; ++j) hv[j] = (_Float16)row[j];
        }
        *(half8*)(pw + (size_t)(g * 64 + nt * 16 + kt) * 512 + l * 8) = hv;
    }
}

// ---------------------------------------------------------------------------
// Pack w_label into f16 A-frag order with l-major columns (unchanged).
// ---------------------------------------------------------------------------
__global__ __launch_bounds__(256) void pack_label(const float* __restrict__ w_label,
                                                  _Float16* __restrict__ gp) {
    int ct = blockIdx.x;               // 0..39
    int tid = threadIdx.x;
    int l = tid & 63;
    int kq = tid >> 6;
    int hi = l >> 5;
    int outcol = ct * 32 + (l & 31);
    int n = outcol & 127;
    int lab = outcol >> 7;
#pragma unroll
    for (int p2 = 0; p2 < 4; ++p2) {
        int kt = p2 * 4 + kq;
        int k0 = kt * 16 + hi * 8;
        int p = k0 >> 7;
        int m0 = k0 & 127;
        half8 hv;
#pragma unroll
        for (int j = 0; j < 8; ++j)
            hv[j] = (_Float16)w_label[(((size_t)p * MDIM + m0 + j) * MDIM + n) * NL + lab];
        *(half8*)(gp + (size_t)(ct * 16 + kt) * 512 + l * 8) = hv;
    }
}

// ---------------------------------------------------------------------------
// Chain kernel v7: 256 blocks x 256 threads (4 waves = 4 n-tiles), TB=64.
// Each wave computes TWO 32-row groups with the SAME in-register A frags
// (A reuse x2, no twin duplication -> 64 VMEM instr/step/CU).
// A double-buffered in registers (128 VGPR), pair-unrolled loop.
// __launch_bounds__(256,1) -> 512-VGPR budget: no pressure to sink prefetch.
// Carry double-buffered in LDS, one lgkm-only barrier per step.
// x loads issued BEFORE A prefetch so their waits never drain A.
// ---------------------------------------------------------------------------
__global__ __launch_bounds__(256, 1) void chain_mfma(
        const float* __restrict__ x, const float* __restrict__ w0,
        const float* __restrict__ w_end, const _Float16* __restrict__ pw,
        float* __restrict__ leftT, float* __restrict__ rightT) {
    __shared__ _Float16 cbuf[2][64 * 128];   // 2 x 16 KB carry

    int bid = blockIdx.x;
    bool is_left = bid < 128;
    int bbase = (is_left ? bid : bid - 128) * 64;
    int tid = threadIdx.x;
    int l = tid & 63;
    int nt = tid >> 6;        // wave = n-tile
    int bl = l & 31;
    int hi = l >> 5;

    int nsteps = is_left ? LSTEPS : RSTEPS;
    int gbase = is_left ? 0 : LSTEPS;
    float* outT = is_left ? leftT : rightT;

    // --- initial carry into cbuf[0] (256 threads cover 64 rows x 128 cols)
    {
        const float* wst = is_left ? w0 : w_end;
        int pos0 = is_left ? 0 : (DIM - 1);
        int b = tid >> 2;                        // 0..63
        const float2 xv0 = *(const float2*)(x + ((size_t)(bbase + b) * DIM + pos0) * 2);
#pragma unroll
        for (int h = 0; h < 4; ++h) {
            int nb = (tid & 3) * 4 + h;          // 0..15
            half8 hv;
#pragma unroll
            for (int j = 0; j < 8; ++j) {
                int n = nb * 8 + j;
                hv[j] = (_Float16)(xv0.x * wst[n] + xv0.y * wst[MDIM + n]);
            }
            int phys = nb ^ (b & 15);
            *(half8*)&cbuf[0][b * 128 + phys * 8] = hv;
        }
    }

    // per-wave A base: frag kt at pwb + step*65536 + kt*1024 (bytes)
    const char* pwb = (const char*)pw + (size_t)(gbase * 64 + nt * 16) * 1024
                    + (size_t)l * 16;
    const float* xr0 = x + (size_t)(bbase + bl) * DIM * 2;        // row group 0
    const float* xr1 = x + (size_t)(bbase + 32 + bl) * DIM * 2;   // row group 1

    half8 A0[16], A1[16];
#pragma unroll
    for (int kt = 0; kt < 16; ++kt)
        A0[kt] = *(const half8*)(pwb + kt * 1024);
    int p00 = (is_left ? 1 : DIM - 2) * 2;
    float2 xc0 = *(const float2*)(xr0 + p00);
    float2 xc1 = *(const float2*)(xr1 + p00);

    __syncthreads();   // carry init visible

    int npairs = nsteps >> 1;          // 48 for both chains
    bool odd = nsteps & 1;             // left: 1, right: 0
    int last = nsteps - 1;

#pragma unroll 1
    for (int sp = 0; sp < npairs; ++sp) {
        int s0 = 2 * sp;
        // ---------- even step s0: consume A0, prefetch A1 <- step s0+1 ----------
        {
            // x first (older than A prefetch -> its waits never drain A)
            int npos = (is_left ? (2 + s0) : (DIM - 3 - s0)) * 2;
            float2 xn0 = *(const float2*)(xr0 + npos);
            float2 xn1 = *(const float2*)(xr1 + npos);
            const char* pn = pwb + (size_t)(s0 + 1) * 65536;
#pragma unroll
            for (int kt = 0; kt < 16; ++kt)
                A1[kt] = *(const half8*)(pn + kt * 1024);

            half8 bf0[8], bf1[8];
#pragma unroll
            for (int q = 0; q < 8; ++q) {
                int nb = q * 2 + hi;
                int phys = nb ^ (bl & 15);       // (bl+32)&15 == bl&15
                bf0[q] = *(const half8*)&cbuf[0][bl * 128 + phys * 8];
                bf1[q] = *(const half8*)&cbuf[0][(bl + 32) * 128 + phys * 8];
            }
            float16v a00 = {}, a01 = {}, a10 = {}, a11 = {};
#pragma unroll
            for (int kt = 0; kt < 8; ++kt) {     // 4 independent MFMA chains
                a00 = __builtin_amdgcn_mfma_f32_32x32x16_f16(A0[kt], bf0[kt], a00, 0, 0, 0);
                a10 = __builtin_amdgcn_mfma_f32_32x32x16_f16(A0[kt], bf1[kt], a10, 0, 0, 0);
                a01 = __builtin_amdgcn_mfma_f32_32x32x16_f16(A0[kt + 8], bf0[kt], a01, 0, 0, 0);
                a11 = __builtin_amdgcn_mfma_f32_32x32x16_f16(A0[kt + 8], bf1[kt], a11, 0, 0, 0);
            }
            // epilogue (even step is never the final step)
#pragma unroll
            for (int rq = 0; rq < 4; ++rq) {
                int nb = nt * 4 + rq;
                int phys = nb ^ (bl & 15);
                union { _Float16 h[4]; uint2 u; } t0, t1;
#pragma unroll
                for (int r = 0; r < 4; ++r) {
                    t0.h[r] = (_Float16)(xc0.x * a00[rq * 4 + r] + xc0.y * a01[rq * 4 + r]);
                    t1.h[r] = (_Float16)(xc1.x * a10[rq * 4 + r] + xc1.y * a11[rq * 4 + r]);
                }
                *(uint2*)&cbuf[1][bl * 128 + phys * 8 + hi * 4] = t0.u;
                *(uint2*)&cbuf[1][(bl + 32) * 128 + phys * 8 + hi * 4] = t1.u;
            }
            BARRIER_LGKM();
            xc0 = xn0; xc1 = xn1;
        }
        // ---------- odd step s1 = s0+1: consume A1, prefetch A0 <- s0+2 ----------
        {
            int s1 = s0 + 1;
            int pf = (s0 + 2 <= last) ? (s0 + 2) : last;   // clamp (harmless reload)
            int nposc = (is_left ? (1 + pf) : (DIM - 2 - pf)) * 2;
            float2 xn0 = *(const float2*)(xr0 + nposc);
            float2 xn1 = *(const float2*)(xr1 + nposc);
            const char* pn = pwb + (size_t)pf * 65536;
#pragma unroll
            for (int kt = 0; kt < 16; ++kt)
                A0[kt] = *(const half8*)(pn + kt * 1024);

            half8 bf0[8], bf1[8];
#pragma unroll
            for (int q = 0; q < 8; ++q) {
                int nb = q * 2 + hi;
                int phys = nb ^ (bl & 15);
                bf0[q] = *(const half8*)&cbuf[1][bl * 128 + phys * 8];
                bf1[q] = *(const half8*)&cbuf[1][(bl + 32) * 128 + phys * 8];
            }
            float16v a00 = {}, a01 = {}, a10 = {}, a11 = {};
#pragma unroll
            for (int kt = 0; kt < 8; ++kt) {
                a00 = __builtin_amdgcn_mfma_f32_32x32x16_f16(A1[kt], bf0[kt], a00, 0, 0, 0);
                a10 = __builtin_amdgcn_mfma_f32_32x32x16_f16(A1[kt], bf1[kt], a10, 0, 0, 0);
                a01 = __builtin_amdgcn_mfma_f32_32x32x16_f16(A1[kt + 8], bf0[kt], a01, 0, 0, 0);
                a11 = __builtin_amdgcn_mfma_f32_32x32x16_f16(A1[kt + 8], bf1[kt], a11, 0, 0, 0);
            }
            if (s1 == last) {
                // final step (right chain): store fp32 transposed [n][BATCH]
#pragma unroll
                for (int r = 0; r < 16; ++r) {
                    int n = nt * 32 + (r & 3) + 8 * (r >> 2) + 4 * hi;
                    outT[(size_t)n * BATCH + bbase + bl] = xc0.x * a00[r] + xc0.y * a01[r];
                    outT[(size_t)n * BATCH + bbase + 32 + bl] = xc1.x * a10[r] + xc1.y * a11[r];
                }
            } else {
#pragma unroll
                for (int rq = 0; rq < 4; ++rq) {
                    int nb = nt * 4 + rq;
                    int phys = nb ^ (bl & 15);
                    union { _Float16 h[4]; uint2 u; } t0, t1;
#pragma unroll
                    for (int r = 0; r < 4; ++r) {
                        t0.h[r] = (_Float16)(xc0.x * a00[rq * 4 + r] + xc0.y * a01[rq * 4 + r]);
                        t1.h[r] = (_Float16)(xc1.x * a10[rq * 4 + r] + xc1.y * a11[rq * 4 + r]);
                    }
                    *(uint2*)&cbuf[0][bl * 128 + phys * 8 + hi * 4] = t0.u;
                    *(uint2*)&cbuf[0][(bl + 32) * 128 + phys * 8 + hi * 4] = t1.u;
                }
                BARRIER_LGKM();
            }
            xc0 = xn0; xc1 = xn1;
        }
    }

    if (odd) {   // tail step = nsteps-1 (left chain), consume A0
        half8 bf0[8], bf1[8];
#pragma unroll
        for (int q = 0; q < 8; ++q) {
            int nb = q * 2 + hi;
            int phys = nb ^ (bl & 15);
            bf0[q] = *(const half8*)&cbuf[0][bl * 128 + phys * 8];
            bf1[q] = *(const half8*)&cbuf[0][(bl + 32) * 128 + phys * 8];
        }
        float16v a00 = {}, a01 = {}, a10 = {}, a11 = {};
#pragma unroll
        for (int kt = 0; kt < 8; ++kt) {
            a00 = __builtin_amdgcn_mfma_f32_32x32x16_f16(A0[kt], bf0[kt], a00, 0, 0, 0);
            a10 = __builtin_amdgcn_mfma_f32_32x32x16_f16(A0[kt], bf1[kt], a10, 0, 0, 0);
            a01 = __builtin_amdgcn_mfma_f32_32x32x16_f16(A0[kt + 8], bf0[kt], a01, 0, 0, 0);
            a11 = __builtin_amdgcn_mfma_f32_32x32x16_f16(A0[kt + 8], bf1[kt], a11, 0, 0, 0);
        }
#pragma unroll
        for (int r = 0; r < 16; ++r) {
            int n = nt * 32 + (r & 3) + 8 * (r >> 2) + 4 * hi;
            outT[(size_t)n * BATCH + bbase + bl] = xc0.x * a00[r] + xc0.y * a01[r];
            outT[(size_t)n * BATCH + bbase + 32 + bl] = xc1.x * a10[r] + xc1.y * a11[r];
        }
    }
}

// ---------------------------------------------------------------------------
// Label contraction via MFMA (unchanged from rounds 3-6).
// ---------------------------------------------------------------------------
__global__ __launch_bounds__(256, 2) void label_mfma(
        const float* __restrict__ x, const _Float16* __restrict__ gp,
        const float* __restrict__ leftT, const float* __restrict__ rightT,
        float* __restrict__ out) {
    __shared__ _Float16 R[32 * 256];     // 16 KB
    __shared__ float pl[4][32][5];
    __shared__ float xl_s[32][2];

    int bx = blockIdx.x;                 // 0/1 -> labels [bx*5, +5)
    int bbase = blockIdx.y * 32;
    int tid = threadIdx.x;
    int l = tid & 63, nt = tid >> 6, bl = l & 31, hi = l >> 5;

    if (tid < 32) {
        const float2 v = *(const float2*)(x + ((size_t)(bbase + tid) * DIM + POSL) * 2);
        xl_s[tid][0] = v.x; xl_s[tid][1] = v.y;
    }
    __syncthreads();

#pragma unroll
    for (int q = 0; q < 4; ++q) {
        int id = tid + q * 256;          // 0..1023
        int m = id >> 3;
        int b4 = (id & 7) * 4;
        float4 v = *(const float4*)&leftT[(size_t)m * BATCH + bbase + b4];
        float vv[4] = {v.x, v.y, v.z, v.w};
#pragma unroll
        for (int bi = 0; bi < 4; ++bi) {
            int b = b4 + bi;
            int kb0 = m >> 3;
            int ph0 = (kb0 & 16) | ((kb0 ^ b) & 15);
            R[b * 256 + ph0 * 8 + (m & 7)] = (_Float16)(xl_s[b][0] * vv[bi]);
            int kb1 = kb0 + 16;
            int ph1 = (kb1 & 16) | ((kb1 ^ b) & 15);
            R[b * 256 + ph1 * 8 + (m & 7)] = (_Float16)(xl_s[b][1] * vv[bi]);
        }
    }

    float rv[16];
#pragma unroll
    for (int r = 0; r < 16; ++r) {
        int n = nt * 32 + (r & 3) + 8 * (r >> 2) + 4 * hi;
        rv[r] = rightT[(size_t)n * BATCH + bbase + bl];
    }
    __syncthreads();

    half8 rf[16];
#pragma unroll
    for (int kt = 0; kt < 16; ++kt) {
        int kb = kt * 2 + hi;
        int ph = (kb & 16) | ((kb ^ bl) & 15);
        rf[kt] = *(const half8*)&R[bl * 256 + ph * 8];
    }

    int l0 = bx * 5;
    float outv[5];
#pragma unroll
    for (int li = 0; li < 5; ++li) {
        int ct = (l0 + li) * 4 + nt;
        float16v acc = {};
#pragma unroll
        for (int kt = 0; kt < 16; ++kt) {
            half8 a = *(const half8*)(gp + (size_t)(ct * 16 + kt) * 512 + l * 8);
            acc = __builtin_amdgcn_mfma_f32_32x32x16_f16(a, rf[kt], acc, 0, 0, 0);
        }
        float p = 0.f;
#pragma unroll
        for (int r = 0; r < 16; ++r) p += acc[r] * rv[r];
        p += __shfl_xor(p, 32, 64);
        outv[li] = p;
    }
    if (hi == 0) {
#pragma unroll
        for (int li = 0; li < 5; ++li) pl[nt][bl][li] = outv[li];
    }
    __syncthreads();
    if (tid < 160) {
        int b = tid / 5, li = tid % 5;
        out[(size_t)(bbase + b) * NL + l0 + li] =
            pl[0][b][li] + pl[1][b][li] + pl[2][b][li] + pl[3][b][li];
    }
}

// ---------------------------------------------------------------------------
extern "C" void kernel_launch(void* const* d_in, const int* in_sizes, int n_in,
                              void* d_out, int out_size, void* d_ws, size_t ws_size,
                              hipStream_t stream) {
    const float* x       = (const float*)d_in[0];
    const float* w0      = (const float*)d_in[1];
    const float* w_left  = (const float*)d_in[2];
    const float* w_label = (const float*)d_in[3];
    const float* w_right = (const float*)d_in[4];
    const float* w_end   = (const float*)d_in[5];

    _Float16* pw = (_Float16*)d_ws;                               // 12.64 MB
    _Float16* gp = pw + (size_t)NSTEPS * 64 * 512;                // 0.66 MB
    float* leftT  = (float*)(gp + (size_t)40 * 16 * 512);         // 4 MB
    float* rightT = leftT + (size_t)MDIM * BATCH;                 // 4 MB

    pack_w<<<dim3(NSTEPS * 4), 256, 0, stream>>>(w_left, w_right, pw);
    pack_label<<<dim3(40), 256, 0, stream>>>(w_label, gp);
    chain_mfma<<<dim3(256), 256, 0, stream>>>(x, w0, w_end, pw, leftT, rightT);
    label_mfma<<<dim3(2, BATCH / 32), 256, 0, stream>>>(x, gp, leftT, rightT,
                                                        (float*)d_out);
}